// Round 1
// baseline (1779.475 us; speedup 1.0000x reference)
//
#include <hip/hip_runtime.h>

// ---------------------------------------------------------------------------
// CIN++ conv, MI355X. Round 0: bf16-MFMA GEMMs + fused atomic scatter.
//
// Decomposition: ReLU(cat(x_j, attr_e) @ W + b)
//              = ReLU( T[j] + attr_e @ W_bot + b ),  T = x @ W_top
// so the per-edge matmul is a dense streaming GEMM (no gather on the A side).
// BN stats (sum, sumsq per channel) accumulated by GEMM epilogues via
// shuffle-reduced atomics; BN+ReLU applied during the next GEMM's A-load.
// ---------------------------------------------------------------------------

#define NCELLS 32768
#define DDIM   128
#define EUP    524288
#define EDN    524288
#define EB     131072
#define NS     4194304   // NCELLS * DDIM

typedef __attribute__((ext_vector_type(8))) __bf16 bf16x8;
typedef __attribute__((ext_vector_type(4))) float  float4v;

enum { M_T = 0, M_EDGE = 1, M_Z = 2, M_COMB = 3 };

// ---------------------------------------------------------------------------
// Generic 64-row x 128-col MFMA GEMM:  C = A[M x K] @ W[K x 128]  (bf16 MFMA,
// fp32 accumulate).  Block = 256 thr = 4 waves; each wave owns 16 rows x 128
// cols via 8 n-tiles of 16x16x32 MFMA, K consumed 32 per step.
// W staged to LDS transposed (Wt[n][k], pad 136) so B-frags are ds_read_b128.
// Modes:
//   M_T    : C -> outp[row*256 + tcoff + col]                  (T precompute)
//   M_EDGE : v = ReLU(C + bias + T[src[row]]); atomicAdd to h[dst[row]]
//   M_Z    : v = C + bias; store z; per-channel sum/sumsq atomics
//   M_COMB : like M_Z but A is 3-branch concat of z2 (K=384)
// XFORM: A-elements get y = max(a[ch]*v + c[ch], 0) before bf16 conversion
// (applies BN+ReLU of the previous layer on the fly).
// ---------------------------------------------------------------------------
template<int MODE, bool XFORM>
__global__ __launch_bounds__(256) void gemm_k(
    const float* __restrict__ A, const float* __restrict__ W,
    const float* __restrict__ bias, const float* __restrict__ ta,
    const float* __restrict__ tc, const float* __restrict__ Tb,
    const int* __restrict__ eidx, float* __restrict__ outp,
    float* __restrict__ ssum, float* __restrict__ ssq,
    int K, int E, int tcoff)
{
  __shared__ __align__(16) __bf16 Wt[128 * 136];
  __shared__ float sTa[384];
  __shared__ float sTc[384];

  const int tid  = threadIdx.x;
  const int wave = tid >> 6;
  const int lane = tid & 63;
  const int quad = lane >> 4;
  const int l16  = lane & 15;
  const int rowBase = blockIdx.x * 64 + wave * 16;
  const int am = rowBase + l16;          // row this lane loads for A-frags

  float4v acc[8];
#pragma unroll
  for (int nt = 0; nt < 8; ++nt) acc[nt] = (float4v){0.f, 0.f, 0.f, 0.f};

  if (XFORM) {
    for (int i = tid; i < K; i += 256) { sTa[i] = ta[i]; sTc[i] = tc[i]; }
  }

  for (int kc = 0; kc < K; kc += 128) {
    if (kc) __syncthreads();
    // stage W chunk, transposed + bf16
    for (int i = tid; i < 128 * 128; i += 256) {
      int k = i >> 7, n = i & 127;
      Wt[n * 136 + k] = (__bf16)W[(size_t)(kc + k) * 128 + n];
    }
    __syncthreads();

#pragma unroll
    for (int ks = 0; ks < 4; ++ks) {
      const int kk0 = kc + ks * 32 + quad * 8;   // first of this lane's 8 k's
      float av[8];
      if (MODE == M_COMB) {
        const int kb = kk0 >> 7, ch = kk0 & 127;
        const float* ap = A + (size_t)kb * NS + (size_t)am * 128 + ch;
        float4v v0 = *(const float4v*)ap;
        float4v v1 = *(const float4v*)(ap + 4);
#pragma unroll
        for (int j = 0; j < 4; ++j) { av[j] = v0[j]; av[4 + j] = v1[j]; }
      } else {
        const float* ap = A + (size_t)am * 128 + kk0;   // K==128 modes
        float4v v0 = *(const float4v*)ap;
        float4v v1 = *(const float4v*)(ap + 4);
#pragma unroll
        for (int j = 0; j < 4; ++j) { av[j] = v0[j]; av[4 + j] = v1[j]; }
      }
      if (XFORM) {
#pragma unroll
        for (int j = 0; j < 8; ++j)
          av[j] = fmaxf(fmaf(sTa[kk0 + j], av[j], sTc[kk0 + j]), 0.f);
      }
      bf16x8 af;
#pragma unroll
      for (int j = 0; j < 8; ++j) af[j] = (__bf16)av[j];

#pragma unroll
      for (int nt = 0; nt < 8; ++nt) {
        bf16x8 bf = *(const bf16x8*)&Wt[(nt * 16 + l16) * 136 + ks * 32 + quad * 8];
        acc[nt] = __builtin_amdgcn_mfma_f32_16x16x32_bf16(af, bf, acc[nt], 0, 0, 0);
      }
    }
  }

  // ---- epilogue: C element (row = rowBase + quad*4 + r, col = nt*16 + l16)
  const int crow = rowBase + quad * 4;
  if (MODE == M_EDGE) {
    int dsts[4], srcs[4];
#pragma unroll
    for (int r = 0; r < 4; ++r) {
      dsts[r] = eidx[crow + r];        // index[0] = segment (dst)
      srcs[r] = eidx[E + crow + r];    // index[1] = source node j
    }
#pragma unroll
    for (int nt = 0; nt < 8; ++nt) {
      const int col = nt * 16 + l16;
      const float bb = bias[col];
#pragma unroll
      for (int r = 0; r < 4; ++r) {
        float v = acc[nt][r] + bb + Tb[(size_t)srcs[r] * 256 + tcoff + col];
        v = fmaxf(v, 0.f);
        unsafeAtomicAdd(&outp[(size_t)dsts[r] * 128 + col], v);
      }
    }
  } else if (MODE == M_T) {
#pragma unroll
    for (int nt = 0; nt < 8; ++nt) {
      const int col = nt * 16 + l16;
#pragma unroll
      for (int r = 0; r < 4; ++r)
        outp[(size_t)(crow + r) * 256 + tcoff + col] = acc[nt][r];
    }
  } else {  // M_Z / M_COMB: store z (+bias) and accumulate BN stats
#pragma unroll
    for (int nt = 0; nt < 8; ++nt) {
      const int col = nt * 16 + l16;
      const float bb = bias[col];
      float s = 0.f, ss = 0.f;
#pragma unroll
      for (int r = 0; r < 4; ++r) {
        float v = acc[nt][r] + bb;
        outp[(size_t)(crow + r) * 128 + col] = v;
        s += v; ss += v * v;
      }
      // lanes {l16, l16+16, l16+32, l16+48} share col -> reduce across quads
      s  += __shfl_xor(s, 16);  s  += __shfl_xor(s, 32);
      ss += __shfl_xor(ss, 16); ss += __shfl_xor(ss, 32);
      if (quad == 0) {
        unsafeAtomicAdd(&ssum[col], s);
        unsafeAtomicAdd(&ssq[col], ss);
      }
    }
  }
}

// h[k][i][:] = x[i][:] for k=0..2 (GIN self term; messages atomically added)
__global__ __launch_bounds__(256) void init_h(const float* __restrict__ x,
                                              float* __restrict__ h)
{
  size_t i = (size_t)blockIdx.x * 256 + threadIdx.x;   // over NS/4 float4s
  float4v v = ((const float4v*)x)[i];
  ((float4v*)h)[i] = v;
  ((float4v*)(h + NS))[i] = v;
  ((float4v*)(h + 2 * (size_t)NS))[i] = v;
}

// boundary messages: h2[b1[e]] += boundary_attr[b0[e]]
__global__ __launch_bounds__(256) void boundary_scatter(
    const int* __restrict__ bidx, const float* __restrict__ battr,
    float* __restrict__ h2)
{
  int e = blockIdx.x * 2 + (threadIdx.x >> 7);
  int d = threadIdx.x & 127;
  int sb = bidx[e];
  int dn = bidx[EB + e];
  unsafeAtomicAdd(&h2[(size_t)dn * 128 + d], battr[(size_t)sb * 128 + d]);
}

// per-channel BN affine: a = g*rsqrt(var+eps), c = beta - mean*a
__global__ __launch_bounds__(256) void bn_params(
    const float* __restrict__ ssum, const float* __restrict__ ssq,
    const float* __restrict__ g, const float* __restrict__ be,
    float* __restrict__ a, float* __restrict__ c, int nch)
{
  int i = blockIdx.x * 256 + threadIdx.x;
  if (i < nch) {
    float m   = ssum[i] * (1.f / NCELLS);
    float var = ssq[i] * (1.f / NCELLS) - m * m;
    float inv = rsqrtf(var + 1e-5f);
    float ai  = g[i] * inv;
    a[i] = ai;
    c[i] = be[i] - m * ai;
  }
}

__global__ __launch_bounds__(256) void finalize_k(
    const float* __restrict__ z3, const float* __restrict__ a,
    const float* __restrict__ c, float* __restrict__ out)
{
  int idx = blockIdx.x * 256 + threadIdx.x;
  int ch = idx & 127;
  out[idx] = fmaxf(fmaf(a[ch], z3[idx], c[ch]), 0.f);
}

extern "C" void kernel_launch(void* const* d_in, const int* in_sizes, int n_in,
                              void* d_out, int out_size, void* d_ws, size_t ws_size,
                              hipStream_t stream)
{
  (void)in_sizes; (void)n_in; (void)out_size; (void)ws_size;

  const float* x        = (const float*)d_in[0];
  const int*   up_idx   = (const int*)d_in[1];
  const int*   dn_idx   = (const int*)d_in[2];
  const int*   b_idx    = (const int*)d_in[3];
  const float* up_attr  = (const float*)d_in[4];
  const float* dn_attr  = (const float*)d_in[5];
  const float* b_attr   = (const float*)d_in[6];
  const float* mu_w     = (const float*)d_in[7];
  const float* mu_b     = (const float*)d_in[8];
  const float* md_w     = (const float*)d_in[9];
  const float* md_b     = (const float*)d_in[10];
  const float* w1       = (const float*)d_in[11];
  const float* b1       = (const float*)d_in[12];
  const float* g1       = (const float*)d_in[13];
  const float* be1      = (const float*)d_in[14];
  const float* w2       = (const float*)d_in[15];
  const float* b2       = (const float*)d_in[16];
  const float* g2       = (const float*)d_in[17];
  const float* be2      = (const float*)d_in[18];
  const float* cw       = (const float*)d_in[19];
  const float* cb       = (const float*)d_in[20];
  const float* cg       = (const float*)d_in[21];
  const float* cbe      = (const float*)d_in[22];

  // workspace layout (floats); peak ~202 MB
  float* ws    = (float*)d_ws;
  float* T     = ws;                       // N x 256 : [x@Wup_top | x@Wdn_top]
  float* h     = T  + (size_t)NCELLS * 256;  // 3 x N x 128
  float* z1    = h  + 3 * (size_t)NS;
  float* z2    = z1 + 3 * (size_t)NS;
  float* z3    = z2 + 3 * (size_t)NS;        // N x 128
  float* stats = z3 + NS;                    // 1792 floats
  float* prm   = stats + 1792;               // 1792 floats

  hipMemsetAsync(stats, 0, 1792 * sizeof(float), stream);

  // T = x @ W_top (up into cols 0..127, down into cols 128..255)
  gemm_k<M_T, false><<<512, 256, 0, stream>>>(
      x, mu_w, nullptr, nullptr, nullptr, nullptr, nullptr, T, nullptr, nullptr,
      128, 0, 0);
  gemm_k<M_T, false><<<512, 256, 0, stream>>>(
      x, md_w, nullptr, nullptr, nullptr, nullptr, nullptr, T, nullptr, nullptr,
      128, 0, 128);

  init_h<<<NS / 4 / 256, 256, 0, stream>>>(x, h);

  // edge messages: aw = attr @ W_bot, epilogue ReLU(aw + T[src] + b) -> h[dst]
  gemm_k<M_EDGE, false><<<EUP / 64, 256, 0, stream>>>(
      up_attr, mu_w + 128 * 128, mu_b, nullptr, nullptr, T, up_idx, h,
      nullptr, nullptr, 128, EUP, 0);
  gemm_k<M_EDGE, false><<<EDN / 64, 256, 0, stream>>>(
      dn_attr, md_w + 128 * 128, md_b, nullptr, nullptr, T, dn_idx, h + NS,
      nullptr, nullptr, 128, EDN, 128);

  boundary_scatter<<<EB / 2, 256, 0, stream>>>(b_idx, b_attr, h + 2 * (size_t)NS);

  // layer 1: z1[k] = h[k] @ w1[k] + b1[k], stats -> stats[0..383]/[384..767]
  for (int k = 0; k < 3; ++k)
    gemm_k<M_Z, false><<<512, 256, 0, stream>>>(
        h + (size_t)k * NS, w1 + k * 16384, b1 + k * 128, nullptr, nullptr,
        nullptr, nullptr, z1 + (size_t)k * NS, stats + k * 128,
        stats + 384 + k * 128, 128, 0, 0);
  bn_params<<<2, 256, 0, stream>>>(stats, stats + 384, g1, be1, prm, prm + 384, 384);

  // layer 2: A-load applies ReLU(a1*z1+c1)
  for (int k = 0; k < 3; ++k)
    gemm_k<M_Z, true><<<512, 256, 0, stream>>>(
        z1 + (size_t)k * NS, w2 + k * 16384, b2 + k * 128, prm + k * 128,
        prm + 384 + k * 128, nullptr, nullptr, z2 + (size_t)k * NS,
        stats + 768 + k * 128, stats + 1152 + k * 128, 128, 0, 0);
  bn_params<<<2, 256, 0, stream>>>(stats + 768, stats + 1152, g2, be2,
                                   prm + 768, prm + 1152, 384);

  // combine: K=384 concat of ReLU(a2*z2+c2)
  gemm_k<M_COMB, true><<<512, 256, 0, stream>>>(
      z2, cw, cb, prm + 768, prm + 1152, nullptr, nullptr, z3,
      stats + 1536, stats + 1664, 384, 0, 0);
  bn_params<<<1, 256, 0, stream>>>(stats + 1536, stats + 1664, cg, cbe,
                                   prm + 1536, prm + 1664, 128);

  finalize_k<<<NS / 256, 256, 0, stream>>>(z3, prm + 1536, prm + 1664,
                                           (float*)d_out);
}

// Round 3
// 1189.207 us; speedup vs baseline: 1.4964x; 1.4964x over previous
//
#include <hip/hip_runtime.h>

// ---------------------------------------------------------------------------
// CIN++ conv, MI355X. Round 1 (resubmit after infra timeout):
//  - dst-sorted CSR (hist/scan/scatter per launch) -> segmented-reduction
//    epilogue, ~16x fewer fp32 atomics than round 0's scatter-atomic storm
//  - all GEMM weights pre-transposed to bf16 [n][k] (pad 136) in global ws;
//    LDS staging via global_load_lds width=16 (no ds_write conflicts)
//  - T (node @ W_top) stored bf16 -> halved random gather traffic
//  - 3-branch MLP layers batched into one dispatch via blockIdx.y
// ---------------------------------------------------------------------------

#define NCELLS 32768
#define EUP    524288
#define EDN    524288
#define EB     131072
#define NS     4194304          // NCELLS * 128
#define CH_SH  17408            // ushorts per transposed W chunk (128*136)

typedef __attribute__((ext_vector_type(8))) __bf16 bf16x8;
typedef __attribute__((ext_vector_type(4))) float  float4v;

static __device__ __forceinline__ unsigned short f2bf(float v) {
  __bf16 b = (__bf16)v;
  return __builtin_bit_cast(unsigned short, b);
}
static __device__ __forceinline__ float bf2f(unsigned short u) {
  unsigned int x = ((unsigned int)u) << 16;
  return __builtin_bit_cast(float, x);
}

#define GLD_LDS16(gp, lp)                                                    \
  __builtin_amdgcn_global_load_lds(                                          \
      (const __attribute__((address_space(1))) void*)(gp),                   \
      (__attribute__((address_space(3))) void*)(lp), 16, 0, 0)

enum { M_T = 0, M_EDGE = 1, M_Z = 2, M_COMB = 3 };

// ---------------------------------------------------------------------------
// 64-row x 128-col MFMA GEMM; W staged from pre-transposed bf16 global chunks
// via global_load_lds. blockIdx.y = branch (M_T: up/dn halves, M_Z: 3 MLPs).
// ---------------------------------------------------------------------------
template<int MODE, bool XFORM>
__global__ __launch_bounds__(256) void gemm_k(
    const float* __restrict__ A,
    const unsigned short* __restrict__ wsT, int chunk0,
    const float* __restrict__ bias,
    const float* __restrict__ ta, const float* __restrict__ tc,
    const unsigned short* __restrict__ Tb, int tcoff,
    const int* __restrict__ aperm, const int* __restrict__ ssrc,
    const int* __restrict__ sdstg,
    float* __restrict__ outp,
    float* __restrict__ ssum, float* __restrict__ ssq, int K)
{
  __shared__ __align__(16) unsigned short Wt[CH_SH];   // reused as C[64][132]
  __shared__ int   sdst_s[64];
  __shared__ float sTa[384], sTc[384];

  const int tid  = threadIdx.x;
  const int wave = tid >> 6, lane = tid & 63;
  const int quad = lane >> 4, l16 = lane & 15;
  const int br   = blockIdx.y;

  const float* Ab = A;
  const float* biasb = bias;
  const float* tab = ta; const float* tcb = tc;
  float* outb = outp;
  float* ssumb = ssum; float* ssqb = ssq;
  int cidx = chunk0, tco = tcoff;
  if (MODE == M_T) { cidx += 2 * br; tco = 128 * br; }
  if (MODE == M_Z) {
    Ab += (size_t)br * NS; cidx += br; biasb += 128 * br;
    if (XFORM) { tab += 128 * br; tcb += 128 * br; }
    outb += (size_t)br * NS; ssumb += 128 * br; ssqb += 128 * br;
  }

  const int rowBase = blockIdx.x * 64 + wave * 16;
  int arow = (MODE == M_EDGE) ? aperm[rowBase + l16] : (rowBase + l16);

  if (XFORM)
    for (int i = tid; i < K; i += 256) { sTa[i] = tab[i]; sTc[i] = tcb[i]; }

  float4v acc[8];
#pragma unroll
  for (int nt = 0; nt < 8; ++nt) acc[nt] = (float4v){0.f, 0.f, 0.f, 0.f};

  for (int kc = 0; kc < K; kc += 128) {
    // preload this chunk's A fragments (registers) before staging barrier
    float4v pa[4], pb[4];
#pragma unroll
    for (int ks = 0; ks < 4; ++ks) {
      const float* ap;
      if (MODE == M_COMB)
        ap = Ab + (size_t)(kc >> 7) * NS + (size_t)arow * 128 + ks * 32 + quad * 8;
      else
        ap = Ab + (size_t)arow * 128 + ks * 32 + quad * 8;
      pa[ks] = *(const float4v*)ap;
      pb[ks] = *(const float4v*)(ap + 4);
    }

    if (kc) __syncthreads();
    {  // async stage: 34816 B of pre-transposed bf16 W into LDS
      const char* g = (const char*)(wsT + (size_t)(cidx + (kc >> 7)) * CH_SH);
      char* l = (char*)Wt;
      for (int off = wave * 1024; off < 2 * CH_SH; off += 4096)
        GLD_LDS16(g + off + lane * 16, l + off);
    }
    __syncthreads();

#pragma unroll
    for (int ks = 0; ks < 4; ++ks) {
      const int kk0 = kc + ks * 32 + quad * 8;
      float av[8];
#pragma unroll
      for (int j = 0; j < 4; ++j) { av[j] = pa[ks][j]; av[4 + j] = pb[ks][j]; }
      if (XFORM) {
#pragma unroll
        for (int j = 0; j < 8; ++j)
          av[j] = fmaxf(fmaf(sTa[kk0 + j], av[j], sTc[kk0 + j]), 0.f);
      }
      bf16x8 af;
#pragma unroll
      for (int j = 0; j < 8; ++j) af[j] = (__bf16)av[j];
#pragma unroll
      for (int nt = 0; nt < 8; ++nt) {
        bf16x8 bf = *(const bf16x8*)&Wt[(nt * 16 + l16) * 136 + ks * 32 + quad * 8];
        acc[nt] = __builtin_amdgcn_mfma_f32_16x16x32_bf16(af, bf, acc[nt], 0, 0, 0);
      }
    }
  }

  const int crow = rowBase + quad * 4;   // C frag rows: crow..crow+3, col nt*16+l16

  if (MODE == M_T) {
    unsigned short* To = (unsigned short*)outb;
#pragma unroll
    for (int nt = 0; nt < 8; ++nt) {
      const int col = nt * 16 + l16;
#pragma unroll
      for (int r = 0; r < 4; ++r)
        To[(size_t)(crow + r) * 256 + tco + col] = f2bf(acc[nt][r]);
    }
  } else if (MODE == M_EDGE) {
    int srcs[4];
#pragma unroll
    for (int r = 0; r < 4; ++r) srcs[r] = ssrc[crow + r];
    __syncthreads();                       // all waves done reading Wt
    if (tid < 64) sdst_s[tid] = sdstg[blockIdx.x * 64 + tid];
    float* Cb = (float*)Wt;                // 64 x 132 fp32 (33792 B <= 34816)
#pragma unroll
    for (int nt = 0; nt < 8; ++nt) {
      const int col = nt * 16 + l16;
      const float bb = biasb[col];
#pragma unroll
      for (int r = 0; r < 4; ++r) {
        float tv = bf2f(Tb[(size_t)srcs[r] * 256 + tco + col]);
        float v = fmaxf(acc[nt][r] + bb + tv, 0.f);
        Cb[(wave * 16 + quad * 4 + r) * 132 + col] = v;
      }
    }
    __syncthreads();
    // segmented reduction over dst-sorted rows: ~4-6 distinct dsts per block
    const int col = tid & 127, half = tid >> 7;
    const int r0 = half * 32;
    int cur = sdst_s[r0];
    float a = 0.f;
    for (int r = r0; r < r0 + 32; ++r) {
      int d = sdst_s[r];
      if (d != cur) {
        unsafeAtomicAdd(&outb[(size_t)cur * 128 + col], a);
        a = 0.f; cur = d;
      }
      a += Cb[r * 132 + col];
    }
    unsafeAtomicAdd(&outb[(size_t)cur * 128 + col], a);
  } else {  // M_Z / M_COMB: store z, accumulate BN stats
#pragma unroll
    for (int nt = 0; nt < 8; ++nt) {
      const int col = nt * 16 + l16;
      const float bb = biasb[col];
      float s = 0.f, ss = 0.f;
#pragma unroll
      for (int r = 0; r < 4; ++r) {
        float v = acc[nt][r] + bb;
        outb[(size_t)(crow + r) * 128 + col] = v;
        s += v; ss += v * v;
      }
      s  += __shfl_xor(s, 16);  s  += __shfl_xor(s, 32);
      ss += __shfl_xor(ss, 16); ss += __shfl_xor(ss, 32);
      if (quad == 0) {
        unsafeAtomicAdd(&ssumb[col], s);
        unsafeAtomicAdd(&ssqb[col], ss);
      }
    }
  }
}

// transpose + bf16-convert all GEMM weights into 13 chunks of [n*136+k]
__global__ __launch_bounds__(256) void prep_w(
    const float* __restrict__ muw, const float* __restrict__ mdw,
    const float* __restrict__ w1, const float* __restrict__ w2,
    const float* __restrict__ cw, unsigned short* __restrict__ wsT)
{
  const int chunk = blockIdx.y;
  const float* src;
  if      (chunk == 0) src = muw;
  else if (chunk == 1) src = muw + 16384;
  else if (chunk == 2) src = mdw;
  else if (chunk == 3) src = mdw + 16384;
  else if (chunk < 7)  src = w1 + (chunk - 4) * 16384;
  else if (chunk < 10) src = w2 + (chunk - 7) * 16384;
  else                 src = cw + (chunk - 10) * 16384;
  int i = blockIdx.x * 256 + threadIdx.x;   // 0..16383
  int k = i >> 7, n = i & 127;
  wsT[(size_t)chunk * CH_SH + n * 136 + k] = f2bf(src[i]);
}

// histogram of dsts for up / down / boundary into 3 x 32768 counters
__global__ __launch_bounds__(256) void hist3(
    const int* __restrict__ up, const int* __restrict__ dn,
    const int* __restrict__ bnd, int* __restrict__ cnts)
{
  int i = blockIdx.x * 256 + threadIdx.x;
  if (i < EUP) atomicAdd(&cnts[up[i]], 1);
  else if (i < EUP + EDN) atomicAdd(&cnts[32768 + dn[i - EUP]], 1);
  else atomicAdd(&cnts[65536 + bnd[EB + (i - EUP - EDN)]], 1);
}

// per-segment exclusive scan (3 x 32768), writes row_start + scatter cursor
__global__ __launch_bounds__(1024) void scan3(
    const int* __restrict__ cnts, int* __restrict__ rs, int* __restrict__ cur)
{
  __shared__ int part[1024];
  const int seg = blockIdx.x, t = threadIdx.x;
  const int* c = cnts + seg * 32768;
  int local[32]; int s = 0;
#pragma unroll
  for (int i = 0; i < 32; ++i) { local[i] = c[t * 32 + i]; s += local[i]; }
  part[t] = s;
  __syncthreads();
  for (int off = 1; off < 1024; off <<= 1) {
    int v = (t >= off) ? part[t - off] : 0;
    __syncthreads();
    part[t] += v;
    __syncthreads();
  }
  int base = t ? part[t - 1] : 0;
  int* r  = rs  + seg * 32769;
  int* cu = cur + seg * 32768;
#pragma unroll
  for (int i = 0; i < 32; ++i) {
    r[t * 32 + i] = base; cu[t * 32 + i] = base; base += local[i];
  }
  if (t == 1023) r[32768] = part[1023];
}

// scatter edges into dst-sorted order
__global__ __launch_bounds__(256) void scat3(
    const int* __restrict__ up, const int* __restrict__ dn,
    const int* __restrict__ bnd, int* __restrict__ cur,
    int* __restrict__ uperm, int* __restrict__ usrc, int* __restrict__ udst,
    int* __restrict__ dperm, int* __restrict__ dsrc, int* __restrict__ ddst,
    int* __restrict__ bperm)
{
  int i = blockIdx.x * 256 + threadIdx.x;
  if (i < EUP) {
    int d = up[i]; int p = atomicAdd(&cur[d], 1);
    uperm[p] = i; usrc[p] = up[EUP + i]; udst[p] = d;
  } else if (i < EUP + EDN) {
    int e = i - EUP; int d = dn[e]; int p = atomicAdd(&cur[32768 + d], 1);
    dperm[p] = e; dsrc[p] = dn[EDN + e]; ddst[p] = d;
  } else {
    int e = i - EUP - EDN; int d = bnd[EB + e];
    int p = atomicAdd(&cur[65536 + d], 1);
    bperm[p] = bnd[e];                       // battr row id, sorted by dst
  }
}

// h0 = h1 = x (self term; edge messages atomically added on top)
__global__ __launch_bounds__(256) void init_h01(const float* __restrict__ x,
                                                float* __restrict__ h)
{
  size_t i = (size_t)blockIdx.x * 256 + threadIdx.x;
  float4v v = ((const float4v*)x)[i];
  ((float4v*)h)[i] = v;
  ((float4v*)(h + NS))[i] = v;
}

// h2[n] = x[n] + sum over CSR range of battr rows (no atomics)
__global__ __launch_bounds__(256) void bnd_agg(
    const float* __restrict__ x, const float* __restrict__ battr,
    const int* __restrict__ bperm, const int* __restrict__ rs,
    float* __restrict__ h2)
{
  int node = blockIdx.x * 2 + (threadIdx.x >> 7);
  int col  = threadIdx.x & 127;
  float acc = x[(size_t)node * 128 + col];
  int s = rs[node], e = rs[node + 1];
  for (int i = s; i < e; ++i)
    acc += battr[(size_t)bperm[i] * 128 + col];
  h2[(size_t)node * 128 + col] = acc;
}

__global__ __launch_bounds__(256) void bn_params(
    const float* __restrict__ ssum, const float* __restrict__ ssq,
    const float* __restrict__ g, const float* __restrict__ be,
    float* __restrict__ a, float* __restrict__ c, int nch)
{
  int i = blockIdx.x * 256 + threadIdx.x;
  if (i < nch) {
    float m   = ssum[i] * (1.f / NCELLS);
    float var = ssq[i] * (1.f / NCELLS) - m * m;
    float inv = rsqrtf(var + 1e-5f);
    float ai  = g[i] * inv;
    a[i] = ai;
    c[i] = be[i] - m * ai;
  }
}

__global__ __launch_bounds__(256) void finalize_k(
    const float* __restrict__ z3, const float* __restrict__ a,
    const float* __restrict__ c, float* __restrict__ out)
{
  int idx = blockIdx.x * 256 + threadIdx.x;
  int ch = idx & 127;
  out[idx] = fmaxf(fmaf(a[ch], z3[idx], c[ch]), 0.f);
}

extern "C" void kernel_launch(void* const* d_in, const int* in_sizes, int n_in,
                              void* d_out, int out_size, void* d_ws, size_t ws_size,
                              hipStream_t stream)
{
  (void)in_sizes; (void)n_in; (void)out_size; (void)ws_size;

  const float* x       = (const float*)d_in[0];
  const int*   up_idx  = (const int*)d_in[1];
  const int*   dn_idx  = (const int*)d_in[2];
  const int*   b_idx   = (const int*)d_in[3];
  const float* up_attr = (const float*)d_in[4];
  const float* dn_attr = (const float*)d_in[5];
  const float* b_attr  = (const float*)d_in[6];
  const float* mu_w    = (const float*)d_in[7];
  const float* mu_b    = (const float*)d_in[8];
  const float* md_w    = (const float*)d_in[9];
  const float* md_b    = (const float*)d_in[10];
  const float* w1      = (const float*)d_in[11];
  const float* b1      = (const float*)d_in[12];
  const float* g1      = (const float*)d_in[13];
  const float* be1     = (const float*)d_in[14];
  const float* w2      = (const float*)d_in[15];
  const float* b2      = (const float*)d_in[16];
  const float* g2      = (const float*)d_in[17];
  const float* be2     = (const float*)d_in[18];
  const float* cw      = (const float*)d_in[19];
  const float* cb      = (const float*)d_in[20];
  const float* cg      = (const float*)d_in[21];
  const float* cbe     = (const float*)d_in[22];

  // ---- workspace layout (z2 aliases h, z3 aliases z1 -> ~132 MB peak)
  float* ws = (float*)d_ws;
  unsigned short* T = (unsigned short*)ws;          // N x 256 bf16
  float* h     = ws + NS;                           // 3 x NS  (also z2)
  float* z1    = h + 3 * (size_t)NS;                // 3 x NS  (also z3)
  float* z2    = h;
  float* z3    = z1;
  float* stats = z1 + 3 * (size_t)NS;               // 1792
  float* prm   = stats + 1792;                      // 1792
  unsigned short* wsT = (unsigned short*)(prm + 1792);  // 13 * 17408 ushorts
  int* cnts  = (int*)(wsT + 13 * CH_SH);            // 3 x 32768
  int* cur   = cnts + 3 * 32768;
  int* rs    = cur + 3 * 32768;                     // 3 x 32769
  int* uperm = rs + 3 * 32769 + 1;
  int* usrc  = uperm + EUP;
  int* udst  = usrc + EUP;
  int* dperm = udst + EUP;
  int* dsrc  = dperm + EDN;
  int* ddst  = dsrc + EDN;
  int* bperm = ddst + EDN;

  hipMemsetAsync(stats, 0, 1792 * sizeof(float), stream);
  hipMemsetAsync(cnts, 0, 3 * 32768 * sizeof(int), stream);

  prep_w<<<dim3(64, 13), 256, 0, stream>>>(mu_w, md_w, w1, w2, cw, wsT);
  hist3<<<4608, 256, 0, stream>>>(up_idx, dn_idx, b_idx, cnts);
  scan3<<<3, 1024, 0, stream>>>(cnts, rs, cur);
  scat3<<<4608, 256, 0, stream>>>(up_idx, dn_idx, b_idx, cur,
                                  uperm, usrc, udst, dperm, dsrc, ddst, bperm);

  // T = x @ W_top for up (cols 0-127) and down (cols 128-255), bf16
  gemm_k<M_T, false><<<dim3(512, 2), 256, 0, stream>>>(
      x, wsT, 0, nullptr, nullptr, nullptr, nullptr, 0,
      nullptr, nullptr, nullptr, (float*)T, nullptr, nullptr, 128);

  init_h01<<<4096, 256, 0, stream>>>(x, h);

  // edge GEMMs over dst-sorted edges, segmented-reduction epilogue
  gemm_k<M_EDGE, false><<<dim3(8192, 1), 256, 0, stream>>>(
      up_attr, wsT, 1, mu_b, nullptr, nullptr, T, 0,
      uperm, usrc, udst, h, nullptr, nullptr, 128);
  gemm_k<M_EDGE, false><<<dim3(8192, 1), 256, 0, stream>>>(
      dn_attr, wsT, 3, md_b, nullptr, nullptr, T, 128,
      dperm, dsrc, ddst, h + NS, nullptr, nullptr, 128);

  bnd_agg<<<16384, 256, 0, stream>>>(x, b_attr, bperm, rs + 2 * 32769,
                                     h + 2 * (size_t)NS);

  // layer 1 (3 branches batched)
  gemm_k<M_Z, false><<<dim3(512, 3), 256, 0, stream>>>(
      h, wsT, 4, b1, nullptr, nullptr, nullptr, 0,
      nullptr, nullptr, nullptr, z1, stats, stats + 384, 128);
  bn_params<<<2, 256, 0, stream>>>(stats, stats + 384, g1, be1, prm, prm + 384, 384);

  // layer 2 (BN+ReLU of layer 1 applied on A-load)
  gemm_k<M_Z, true><<<dim3(512, 3), 256, 0, stream>>>(
      z1, wsT, 7, b2, prm, prm + 384, nullptr, 0,
      nullptr, nullptr, nullptr, z2, stats + 768, stats + 1152, 384 == 384 ? 128 : 128);
  bn_params<<<2, 256, 0, stream>>>(stats + 768, stats + 1152, g2, be2,
                                   prm + 768, prm + 1152, 384);

  // combine (K=384 over 3-branch concat)
  gemm_k<M_COMB, true><<<dim3(512, 1), 256, 0, stream>>>(
      z2, wsT, 10, cb, prm + 768, prm + 1152, nullptr, 0,
      nullptr, nullptr, nullptr, z3, stats + 1536, stats + 1664, 384);
  bn_params<<<1, 256, 0, stream>>>(stats + 1536, stats + 1664, cg, cbe,
                                   prm + 1536, prm + 1664, 128);

  finalize_k<<<16384, 256, 0, stream>>>(z3, prm + 1536, prm + 1664,
                                        (float*)d_out);
}